// Round 4
// baseline (425.691 us; speedup 1.0000x reference)
//
#include <hip/hip_runtime.h>
#include <stdint.h>

// B=4, S=2048, D=1024, H=16, Hd=64, M=8192.
// Pipeline: cast x -> bf16; merged W^T casts; merged QKV GEMM (Q pre-scaled
// by log2e/8); V transpose to [bh][hd][s]; flash attn computing S^T = K@Q^T
// so exp2(scores) form PV A-frags in-register (key-permutation trick, no P
// LDS round-trip); O-projection GEMM (fp32 out).
// R4: attn = 512-thread blocks, BK=128 (16 barriers), dbuf LDS, 16 waves/CU.

typedef float f32x4 __attribute__((ext_vector_type(4)));
typedef __bf16 bf16x4 __attribute__((ext_vector_type(4)));
typedef __bf16 bf16x8 __attribute__((ext_vector_type(8)));
typedef uint32_t u32x4 __attribute__((ext_vector_type(4)));

#define MFMA16(a, b, c) __builtin_amdgcn_mfma_f32_16x16x32_bf16((a), (b), (c), 0, 0, 0)

// Q pre-scale: log2(e)/8 so attn does p = exp2(Q'.K) = e^{QK/8} (unnormalized)
#define QSCALE 0.1803368801111204f

__device__ __forceinline__ unsigned short f2bf(float f) {
  union { float f; uint32_t u; } c; c.f = f;
  uint32_t u = c.u;
  return (unsigned short)((u + 0x7fffu + ((u >> 16) & 1u)) >> 16);  // RNE
}

// ---------------------------------------------------------------- casts
__global__ __launch_bounds__(256) void cast_x_kernel(const float* __restrict__ in,
                                                     unsigned short* __restrict__ out,
                                                     int n4) {
  int i = blockIdx.x * 256 + threadIdx.x;
  if (i >= n4) return;
  float4 v = ((const float4*)in)[i];
  ushort4 o;
  o.x = f2bf(v.x); o.y = f2bf(v.y); o.z = f2bf(v.z); o.w = f2bf(v.w);
  ((ushort4*)out)[i] = o;
}

// 4 weights [k][n] fp32 -> Wt [n][k] bf16, z selects matrix; dst contiguous.
__global__ __launch_bounds__(256) void transpose_cast4(const float* __restrict__ W0,
                                                       const float* __restrict__ W1,
                                                       const float* __restrict__ W2,
                                                       const float* __restrict__ W3,
                                                       unsigned short* __restrict__ Wt) {
  __shared__ float tile[32][33];
  const int z = blockIdx.z;
  const float* W = (z == 0) ? W0 : (z == 1) ? W1 : (z == 2) ? W2 : W3;
  unsigned short* dst = Wt + (size_t)z * 1048576;
  int k0 = blockIdx.x * 32, n0 = blockIdx.y * 32;
  int tx = threadIdx.x, ty = threadIdx.y;
#pragma unroll
  for (int i = 0; i < 32; i += 8)
    tile[ty + i][tx] = W[(size_t)(k0 + ty + i) * 1024 + n0 + tx];
  __syncthreads();
#pragma unroll
  for (int i = 0; i < 32; i += 8)
    dst[(size_t)(n0 + ty + i) * 1024 + k0 + tx] = f2bf(tile[tx][ty + i]);
}

// ---------------------------------------------------------------- GEMM
// MODE 0: O-proj. out fp32 [8192][1024], bias b0.
// MODE 1: merged QKV. Bt = [3072][1024], out = QKV bf16 base (3 x 8388608),
//         scatter to [b,h,s,hd]; Q (mb==0) scaled by QSCALE. biases b0,b1,b2.
template <int MODE>
__global__ __launch_bounds__(256) void gemm128(const unsigned short* __restrict__ A,
                                               const unsigned short* __restrict__ Bt,
                                               const float* __restrict__ b0,
                                               const float* __restrict__ b1,
                                               const float* __restrict__ b2,
                                               void* __restrict__ out) {
  constexpr int Kd = 1024;
  __shared__ unsigned short sm[128 * 32 + 32 * 128];
  unsigned short* As = sm;
  unsigned short* Bs = sm + 128 * 32;
  auto lds3 = (__attribute__((address_space(3))) char*)sm;

  const int tid = threadIdx.x;
  const int wave = tid >> 6, lane = tid & 63, quad = lane >> 4, l16 = lane & 15;
  const int wm = wave >> 1, wn = wave & 1;
  const int bm = blockIdx.y * 128, bn = blockIdx.x * 128;

  f32x4 acc[4][4] = {};

  for (int k0 = 0; k0 < Kd; k0 += 32) {
#pragma unroll
    for (int j = 0; j < 2; ++j) {
      int i = (wave * 2 + j) * 64 + lane;  // 16B-chunk index 0..511
      const unsigned short* ga = A + (size_t)(bm + (i >> 2)) * Kd + k0 + (i & 3) * 8;
      __builtin_amdgcn_global_load_lds(
          (const __attribute__((address_space(1))) void*)ga,
          (__attribute__((address_space(3))) void*)(lds3 + (size_t)(wave * 2 + j) * 1024),
          16, 0, 0);
      const unsigned short* gb = Bt + (size_t)(bn + (i >> 2)) * Kd + k0 + (i & 3) * 8;
      __builtin_amdgcn_global_load_lds(
          (const __attribute__((address_space(1))) void*)gb,
          (__attribute__((address_space(3))) void*)(lds3 + 8192 + (size_t)(wave * 2 + j) * 1024),
          16, 0, 0);
    }
    __syncthreads();

    bf16x8 af[4], bfv[4];
#pragma unroll
    for (int i = 0; i < 4; ++i)
      af[i] = *(const bf16x8*)(As + (wm * 64 + i * 16 + l16) * 32 + quad * 8);
#pragma unroll
    for (int n = 0; n < 4; ++n)
      bfv[n] = *(const bf16x8*)(Bs + (wn * 64 + n * 16 + l16) * 32 + quad * 8);
#pragma unroll
    for (int i = 0; i < 4; ++i)
#pragma unroll
      for (int n = 0; n < 4; ++n)
        acc[i][n] = MFMA16(af[i], bfv[n], acc[i][n]);
    __syncthreads();
  }

  // epilogue: C/D layout col=lane&15, row=quad*4+reg
  const int mb = bn >> 10;  // matrix id for MODE 1 (block never straddles: 1024%128==0)
  const float* bias = (MODE == 0) ? b0 : (mb == 0 ? b0 : (mb == 1 ? b1 : b2));
  const float scale = (MODE == 1 && mb == 0) ? QSCALE : 1.0f;
  unsigned short* oq = (MODE == 1) ? ((unsigned short*)out + (size_t)mb * 8388608u) : nullptr;

#pragma unroll
  for (int i = 0; i < 4; ++i) {
    const int row0 = bm + wm * 64 + i * 16 + quad * 4;
#pragma unroll
    for (int n = 0; n < 4; ++n) {
      const int col = bn + wn * 64 + n * 16 + l16;
      const int cl = col & 1023;
      const float bv = bias[cl];
#pragma unroll
      for (int r = 0; r < 4; ++r) {
        float v = (acc[i][n][r] + bv) * scale;
        if (MODE == 0) {
          ((float*)out)[(size_t)(row0 + r) * 1024 + col] = v;
        } else {
          int rr = row0 + r;
          int b = rr >> 11, s = rr & 2047;
          int h = cl >> 6, hd = cl & 63;
          oq[((size_t)(b * 16 + h) * 2048 + s) * 64 + hd] = f2bf(v);
        }
      }
    }
  }
}

// ---------------------------------------------------------------- V transpose
// Vb [bh][s][64] bf16 -> VtG [bh][64][2048] bf16.
__global__ __launch_bounds__(256) void transpose_v(const unsigned short* __restrict__ Vb,
                                                   unsigned short* __restrict__ VtG) {
  __shared__ uint32_t t32[64][33];
  const int bh = blockIdx.y, s0 = blockIdx.x * 64;
  const int tid = threadIdx.x;
  const size_t hbase = (size_t)bh * 131072;
#pragma unroll
  for (int it = 0; it < 2; ++it) {
    int c = tid + it * 256;
    int sr = c >> 3, o4 = (c & 7) * 4;
    u32x4 v = *(const u32x4*)(Vb + hbase + (size_t)(s0 + sr) * 64 + o4 * 2);
    t32[sr][o4] = v[0]; t32[sr][o4 + 1] = v[1];
    t32[sr][o4 + 2] = v[2]; t32[sr][o4 + 3] = v[3];
  }
  __syncthreads();
#pragma unroll
  for (int it = 0; it < 2; ++it) {
    int c = tid + it * 256;
    int hd = c >> 3, so = (c & 7) * 8;
    int hc = hd >> 1, sh = (hd & 1) * 16;
    uint32_t w[4];
#pragma unroll
    for (int j = 0; j < 4; ++j) {
      uint32_t lo = t32[so + 2 * j][hc], hi = t32[so + 2 * j + 1][hc];
      w[j] = ((lo >> sh) & 0xffffu) | (((hi >> sh) & 0xffffu) << 16);
    }
    *(u32x4*)(VtG + hbase + (size_t)hd * 2048 + s0 + so) = *(u32x4*)w;
  }
}

// ---------------------------------------------------------------- flash attention
// Q pre-scaled. Block = (b,h) x 256 q-rows, 512 threads (8 waves x 32 q-rows).
// BK=128 keys per barrier interval, double-buffered LDS.
// S^T = K(A) @ Q^T(B): C-layout puts col=l16=qrow; each lane's exp2'd scores
// form PV A-frags under key permutation sigma(q*8+j) = st*32+(j>>2)*16+q*4+(j&3);
// V B-frags use the same sigma (two b64 chunks from the Vt tile).
__global__ __launch_bounds__(512, 4) void attn_kernel(const unsigned short* __restrict__ Q,
                                                      const unsigned short* __restrict__ K,
                                                      const unsigned short* __restrict__ Vt,
                                                      unsigned short* __restrict__ ctx) {
  const int bh = blockIdx.y;
  const int tid = threadIdx.x;
  const int wave = tid >> 6, lane = tid & 63, quad = lane >> 4, l16 = lane & 15;

  // K: 128 rows x stride 72 (9216 ush); V: 64 rows x stride 132 (8448 ush)
  __shared__ unsigned short sm[2][9216 + 8448];  // 70,656 B total -> 2 blocks/CU

  const size_t hb = (size_t)bh * 131072;
  const int q0 = blockIdx.x * 256 + wave * 32;

  // Q B-frags: B[k=hd][n=qrow]: lane l16 = qrow, k = quad*8+j (+32*hh)
  bf16x8 qf[2][2];
#pragma unroll
  for (int qt = 0; qt < 2; ++qt)
#pragma unroll
    for (int hh = 0; hh < 2; ++hh)
      qf[qt][hh] = *(const bf16x8*)(Q + hb + (size_t)(q0 + qt * 16 + l16) * 64 + hh * 32 + quad * 8);

  f32x4 o[2][4] = {};
  float lacc[2] = {0.f, 0.f};

  // staging: 4 x 16B chunks/thread (2 K + 2 Vt) into regs, then LDS
  const int c0 = tid, c1 = tid + 512;
  const unsigned short* gK0 = K + hb + (size_t)(c0 >> 3) * 64 + (c0 & 7) * 8;
  const unsigned short* gK1 = K + hb + (size_t)(c1 >> 3) * 64 + (c1 & 7) * 8;
  const unsigned short* gV0 = Vt + hb + (size_t)(c0 >> 4) * 2048 + (c0 & 15) * 8;
  const unsigned short* gV1 = Vt + hb + (size_t)(c1 >> 4) * 2048 + (c1 & 15) * 8;
  const int sK0 = (c0 >> 3) * 72 + (c0 & 7) * 8;
  const int sK1 = (c1 >> 3) * 72 + (c1 & 7) * 8;
  const int sV0 = 9216 + (c0 >> 4) * 132 + (c0 & 15) * 8;
  const int sV1 = 9216 + (c1 >> 4) * 132 + (c1 & 15) * 8;

  u32x4 pk0 = *(const u32x4*)gK0, pk1 = *(const u32x4*)gK1;
  u32x4 pv0 = *(const u32x4*)gV0, pv1 = *(const u32x4*)gV1;
  {
    unsigned short* s0b = sm[0];
    *(u32x4*)(s0b + sK0) = pk0; *(u32x4*)(s0b + sK1) = pk1;
    *(u32x4*)(s0b + sV0) = pv0; *(u32x4*)(s0b + sV1) = pv1;
  }
  __syncthreads();

  for (int kb = 0; kb < 2048; kb += 128) {
    const int cur = (kb >> 7) & 1;
    const bool more = (kb + 128) < 2048;
    if (more) {
      pk0 = *(const u32x4*)(gK0 + (size_t)(kb + 128) * 64);
      pk1 = *(const u32x4*)(gK1 + (size_t)(kb + 128) * 64);
      pv0 = *(const u32x4*)(gV0 + kb + 128);
      pv1 = *(const u32x4*)(gV1 + kb + 128);
    }
    const unsigned short* Ks = sm[cur];
    const unsigned short* Vts = sm[cur] + 9216;

#pragma unroll
    for (int st = 0; st < 4; ++st) {
      // scores for key-group st (keys st*32 .. st*32+31), both q-subtiles
      bf16x8 pf[2];
      float ls0 = 0.f, ls1 = 0.f;
#pragma unroll
      for (int kh = 0; kh < 2; ++kh) {
        // K A-frags for subtile ks = 2*st+kh: lane l16 = key, contiguous hd
        const unsigned short* kr = Ks + ((2 * st + kh) * 16 + l16) * 72 + quad * 8;
        bf16x8 kf0 = *(const bf16x8*)kr;
        bf16x8 kf1 = *(const bf16x8*)(kr + 32);
        f32x4 s0 = {0.f, 0.f, 0.f, 0.f}, s1 = {0.f, 0.f, 0.f, 0.f};
        s0 = MFMA16(kf0, qf[0][0], s0); s0 = MFMA16(kf1, qf[0][1], s0);
        s1 = MFMA16(kf0, qf[1][0], s1); s1 = MFMA16(kf1, qf[1][1], s1);
#pragma unroll
        for (int r = 0; r < 4; ++r) {
          float p0 = __builtin_amdgcn_exp2f(s0[r]);
          float p1 = __builtin_amdgcn_exp2f(s1[r]);
          ls0 += p0; ls1 += p1;
          pf[0][kh * 4 + r] = (__bf16)p0;
          pf[1][kh * 4 + r] = (__bf16)p1;
        }
      }
      lacc[0] += ls0; lacc[1] += ls1;

      // PV for this key-group: V B-frags under sigma (two b64 chunks)
#pragma unroll
      for (int os = 0; os < 4; ++os) {
        const unsigned short* rb = Vts + (os * 16 + l16) * 132 + st * 32 + quad * 4;
        bf16x4 a = *(const bf16x4*)rb;
        bf16x4 b2 = *(const bf16x4*)(rb + 16);
        bf16x8 vf = __builtin_shufflevector(a, b2, 0, 1, 2, 3, 4, 5, 6, 7);
        o[0][os] = MFMA16(pf[0], vf, o[0][os]);
        o[1][os] = MFMA16(pf[1], vf, o[1][os]);
      }
    }

    if (more) {
      unsigned short* sn = sm[cur ^ 1];
      *(u32x4*)(sn + sK0) = pk0; *(u32x4*)(sn + sK1) = pk1;
      *(u32x4*)(sn + sV0) = pv0; *(u32x4*)(sn + sV1) = pv1;
    }
    __syncthreads();
  }

  // finalize: reduce l across quads (lane's l16 = qrow), redistribute to
  // C-layout rows (quad*4+r), normalize, store.
  const int b = bh >> 4, h = bh & 15;
#pragma unroll
  for (int qt = 0; qt < 2; ++qt) {
    float l = lacc[qt];
    l += __shfl_xor(l, 16, 64);
    l += __shfl_xor(l, 32, 64);
#pragma unroll
    for (int r = 0; r < 4; ++r) {
      float lr = __shfl(l, quad * 4 + r, 16);
      float inv = 1.0f / lr;
      int s = q0 + qt * 16 + quad * 4 + r;
#pragma unroll
      for (int os = 0; os < 4; ++os)
        ctx[((size_t)(b * 2048 + s)) * 1024 + h * 64 + os * 16 + l16] = f2bf(o[qt][os][r] * inv);
    }
  }
}

// ---------------------------------------------------------------- launch
extern "C" void kernel_launch(void* const* d_in, const int* in_sizes, int n_in,
                              void* d_out, int out_size, void* d_ws, size_t ws_size,
                              hipStream_t stream) {
  const float* x  = (const float*)d_in[0];
  const float* Wq = (const float*)d_in[1];
  const float* bq = (const float*)d_in[2];
  const float* Wk = (const float*)d_in[3];
  const float* bk = (const float*)d_in[4];
  const float* Wv = (const float*)d_in[5];
  const float* bv = (const float*)d_in[6];
  const float* Wo = (const float*)d_in[7];
  const float* bo = (const float*)d_in[8];

  unsigned short* ws = (unsigned short*)d_ws;
  unsigned short* xb    = ws;                    // 8388608 (aliased by VtG later)
  unsigned short* Wtall = ws + 8388608;          // 4*1048576 (Wq^T|Wk^T|Wv^T|Wo^T)
  unsigned short* Wot   = Wtall + 3145728;
  unsigned short* Qb    = Wtall + 4194304;       // 8388608  [bh][s][hd], pre-scaled
  unsigned short* Kb    = Qb + 8388608;          // 8388608
  unsigned short* Vb    = Kb + 8388608;          // 8388608
  unsigned short* VtG   = xb;                    // alias: xb dead after QKV GEMM
  unsigned short* Cb    = Vb;                    // alias: Vb dead after transpose_v

  cast_x_kernel<<<8192, 256, 0, stream>>>(x, xb, 2097152);
  transpose_cast4<<<dim3(32, 32, 4), dim3(32, 8), 0, stream>>>(Wq, Wk, Wv, Wo, Wtall);

  gemm128<1><<<dim3(24, 64), 256, 0, stream>>>(xb, Wtall, bq, bk, bv, Qb);
  transpose_v<<<dim3(32, 64), 256, 0, stream>>>(Vb, VtG);
  attn_kernel<<<dim3(8, 64), 512, 0, stream>>>(Qb, Kb, VtG, Cb);
  gemm128<0><<<dim3(8, 64), 256, 0, stream>>>(Cb, Wot, bo, nullptr, nullptr, d_out);
}

// Round 5
// 278.473 us; speedup vs baseline: 1.5287x; 1.5287x over previous
//
#include <hip/hip_runtime.h>
#include <stdint.h>

// B=4, S=2048, D=1024, H=16, Hd=64, M=8192.
// Pipeline: cast x -> bf16; merged W^T casts; merged QKV GEMM (Q pre-scaled
// by log2e/8); V transpose to [bh][hd][s]; flash attn computing S^T = K@Q^T
// so exp2(scores) form PV A-frags in-register (key-permutation trick, no P
// LDS round-trip); O-projection GEMM (fp32 out).
// R5: attn = 512 threads, two 4-wave groups split the key range (keys 0-1023 /
// 1024-2047), each group dbuf-staged; cross-group (o,l) combine via LDS.
// 73.7KB LDS -> 2 blocks/CU -> 16 waves/CU; wave body identical to R3 (116 VGPR).
// NOTE: __launch_bounds__ 2nd arg acts as min BLOCKS/CU (R4 evidence: (512,4)
// produced a 64-VGPR cap and 1 GB of scratch spill traffic).

typedef float f32x4 __attribute__((ext_vector_type(4)));
typedef __bf16 bf16x4 __attribute__((ext_vector_type(4)));
typedef __bf16 bf16x8 __attribute__((ext_vector_type(8)));
typedef uint32_t u32x4 __attribute__((ext_vector_type(4)));

#define MFMA16(a, b, c) __builtin_amdgcn_mfma_f32_16x16x32_bf16((a), (b), (c), 0, 0, 0)

// Q pre-scale: log2(e)/8 so attn does p = exp2(Q'.K) = e^{QK/8} (unnormalized)
#define QSCALE 0.1803368801111204f

__device__ __forceinline__ unsigned short f2bf(float f) {
  union { float f; uint32_t u; } c; c.f = f;
  uint32_t u = c.u;
  return (unsigned short)((u + 0x7fffu + ((u >> 16) & 1u)) >> 16);  // RNE
}

// ---------------------------------------------------------------- casts
__global__ __launch_bounds__(256) void cast_x_kernel(const float* __restrict__ in,
                                                     unsigned short* __restrict__ out,
                                                     int n4) {
  int i = blockIdx.x * 256 + threadIdx.x;
  if (i >= n4) return;
  float4 v = ((const float4*)in)[i];
  ushort4 o;
  o.x = f2bf(v.x); o.y = f2bf(v.y); o.z = f2bf(v.z); o.w = f2bf(v.w);
  ((ushort4*)out)[i] = o;
}

// 4 weights [k][n] fp32 -> Wt [n][k] bf16, z selects matrix; dst contiguous.
__global__ __launch_bounds__(256) void transpose_cast4(const float* __restrict__ W0,
                                                       const float* __restrict__ W1,
                                                       const float* __restrict__ W2,
                                                       const float* __restrict__ W3,
                                                       unsigned short* __restrict__ Wt) {
  __shared__ float tile[32][33];
  const int z = blockIdx.z;
  const float* W = (z == 0) ? W0 : (z == 1) ? W1 : (z == 2) ? W2 : W3;
  unsigned short* dst = Wt + (size_t)z * 1048576;
  int k0 = blockIdx.x * 32, n0 = blockIdx.y * 32;
  int tx = threadIdx.x, ty = threadIdx.y;
#pragma unroll
  for (int i = 0; i < 32; i += 8)
    tile[ty + i][tx] = W[(size_t)(k0 + ty + i) * 1024 + n0 + tx];
  __syncthreads();
#pragma unroll
  for (int i = 0; i < 32; i += 8)
    dst[(size_t)(n0 + ty + i) * 1024 + k0 + tx] = f2bf(tile[tx][ty + i]);
}

// ---------------------------------------------------------------- GEMM
// MODE 0: O-proj. out fp32 [8192][1024], bias b0.
// MODE 1: merged QKV. Bt = [3072][1024], out = QKV bf16 base (3 x 8388608),
//         scatter to [b,h,s,hd]; Q (mb==0) scaled by QSCALE. biases b0,b1,b2.
template <int MODE>
__global__ __launch_bounds__(256) void gemm128(const unsigned short* __restrict__ A,
                                               const unsigned short* __restrict__ Bt,
                                               const float* __restrict__ b0,
                                               const float* __restrict__ b1,
                                               const float* __restrict__ b2,
                                               void* __restrict__ out) {
  constexpr int Kd = 1024;
  __shared__ unsigned short sm[128 * 32 + 32 * 128];
  unsigned short* As = sm;
  unsigned short* Bs = sm + 128 * 32;
  auto lds3 = (__attribute__((address_space(3))) char*)sm;

  const int tid = threadIdx.x;
  const int wave = tid >> 6, lane = tid & 63, quad = lane >> 4, l16 = lane & 15;
  const int wm = wave >> 1, wn = wave & 1;
  const int bm = blockIdx.y * 128, bn = blockIdx.x * 128;

  f32x4 acc[4][4] = {};

  for (int k0 = 0; k0 < Kd; k0 += 32) {
#pragma unroll
    for (int j = 0; j < 2; ++j) {
      int i = (wave * 2 + j) * 64 + lane;  // 16B-chunk index 0..511
      const unsigned short* ga = A + (size_t)(bm + (i >> 2)) * Kd + k0 + (i & 3) * 8;
      __builtin_amdgcn_global_load_lds(
          (const __attribute__((address_space(1))) void*)ga,
          (__attribute__((address_space(3))) void*)(lds3 + (size_t)(wave * 2 + j) * 1024),
          16, 0, 0);
      const unsigned short* gb = Bt + (size_t)(bn + (i >> 2)) * Kd + k0 + (i & 3) * 8;
      __builtin_amdgcn_global_load_lds(
          (const __attribute__((address_space(1))) void*)gb,
          (__attribute__((address_space(3))) void*)(lds3 + 8192 + (size_t)(wave * 2 + j) * 1024),
          16, 0, 0);
    }
    __syncthreads();

    bf16x8 af[4], bfv[4];
#pragma unroll
    for (int i = 0; i < 4; ++i)
      af[i] = *(const bf16x8*)(As + (wm * 64 + i * 16 + l16) * 32 + quad * 8);
#pragma unroll
    for (int n = 0; n < 4; ++n)
      bfv[n] = *(const bf16x8*)(Bs + (wn * 64 + n * 16 + l16) * 32 + quad * 8);
#pragma unroll
    for (int i = 0; i < 4; ++i)
#pragma unroll
      for (int n = 0; n < 4; ++n)
        acc[i][n] = MFMA16(af[i], bfv[n], acc[i][n]);
    __syncthreads();
  }

  // epilogue: C/D layout col=lane&15, row=quad*4+reg
  const int mb = bn >> 10;  // matrix id for MODE 1 (block never straddles: 1024%128==0)
  const float* bias = (MODE == 0) ? b0 : (mb == 0 ? b0 : (mb == 1 ? b1 : b2));
  const float scale = (MODE == 1 && mb == 0) ? QSCALE : 1.0f;
  unsigned short* oq = (MODE == 1) ? ((unsigned short*)out + (size_t)mb * 8388608u) : nullptr;

#pragma unroll
  for (int i = 0; i < 4; ++i) {
    const int row0 = bm + wm * 64 + i * 16 + quad * 4;
#pragma unroll
    for (int n = 0; n < 4; ++n) {
      const int col = bn + wn * 64 + n * 16 + l16;
      const int cl = col & 1023;
      const float bv = bias[cl];
#pragma unroll
      for (int r = 0; r < 4; ++r) {
        float v = (acc[i][n][r] + bv) * scale;
        if (MODE == 0) {
          ((float*)out)[(size_t)(row0 + r) * 1024 + col] = v;
        } else {
          int rr = row0 + r;
          int b = rr >> 11, s = rr & 2047;
          int h = cl >> 6, hd = cl & 63;
          oq[((size_t)(b * 16 + h) * 2048 + s) * 64 + hd] = f2bf(v);
        }
      }
    }
  }
}

// ---------------------------------------------------------------- V transpose
// Vb [bh][s][64] bf16 -> VtG [bh][64][2048] bf16.
__global__ __launch_bounds__(256) void transpose_v(const unsigned short* __restrict__ Vb,
                                                   unsigned short* __restrict__ VtG) {
  __shared__ uint32_t t32[64][33];
  const int bh = blockIdx.y, s0 = blockIdx.x * 64;
  const int tid = threadIdx.x;
  const size_t hbase = (size_t)bh * 131072;
#pragma unroll
  for (int it = 0; it < 2; ++it) {
    int c = tid + it * 256;
    int sr = c >> 3, o4 = (c & 7) * 4;
    u32x4 v = *(const u32x4*)(Vb + hbase + (size_t)(s0 + sr) * 64 + o4 * 2);
    t32[sr][o4] = v[0]; t32[sr][o4 + 1] = v[1];
    t32[sr][o4 + 2] = v[2]; t32[sr][o4 + 3] = v[3];
  }
  __syncthreads();
#pragma unroll
  for (int it = 0; it < 2; ++it) {
    int c = tid + it * 256;
    int hd = c >> 3, so = (c & 7) * 8;
    int hc = hd >> 1, sh = (hd & 1) * 16;
    uint32_t w[4];
#pragma unroll
    for (int j = 0; j < 4; ++j) {
      uint32_t lo = t32[so + 2 * j][hc], hi = t32[so + 2 * j + 1][hc];
      w[j] = ((lo >> sh) & 0xffffu) | (((hi >> sh) & 0xffffu) << 16);
    }
    *(u32x4*)(VtG + hbase + (size_t)hd * 2048 + s0 + so) = *(u32x4*)w;
  }
}

// ---------------------------------------------------------------- flash attention
// Q pre-scaled. Block = (b,h) x 256 q-rows, 512 threads = 2 key-groups x 4 waves.
// Group g (wave>>2) processes keys [g*1024, g*1024+1024) for all 256 q-rows;
// each wave covers 64 q-rows (4 subtiles). Per group: dbuf LDS K/V tiles of 64
// keys. End: group 1 deposits (o,l) into LDS, group 0 combines + stores.
// S^T = K(A) @ Q^T(B): C-layout puts col=l16=qrow; each lane's exp2'd scores
// form PV A-frags under key permutation sigma(q*8+j) = st*32+(j>>2)*16+q*4+(j&3);
// V B-frags use the same sigma (two b64 chunks from the Vt tile).
__global__ __launch_bounds__(512, 2) void attn_kernel(const unsigned short* __restrict__ Q,
                                                      const unsigned short* __restrict__ K,
                                                      const unsigned short* __restrict__ Vt,
                                                      unsigned short* __restrict__ ctx) {
  const int bh = blockIdx.y;
  const int tid = threadIdx.x;
  const int wave = tid >> 6, lane = tid & 63, quad = lane >> 4, l16 = lane & 15;
  const int grp = wave >> 2, w4 = wave & 3;

  // [grp][buf][ K 64x72 | Vt 64x72 ] ushort = 73728 B -> 2 blocks/CU
  __shared__ unsigned short sm[2][2][9216];

  const size_t hb = (size_t)bh * 131072;
  const int q0 = blockIdx.x * 256 + w4 * 64;

  // Q B-frags: B[k=hd][n=qrow]: lane l16 = qrow, k = quad*8+j (+32*st)
  bf16x8 qf[4][2];
#pragma unroll
  for (int qt = 0; qt < 4; ++qt)
#pragma unroll
    for (int st = 0; st < 2; ++st)
      qf[qt][st] = *(const bf16x8*)(Q + hb + (size_t)(q0 + qt * 16 + l16) * 64 + st * 32 + quad * 8);

  f32x4 o[4][4] = {};
  float lacc[4] = {0.f, 0.f, 0.f, 0.f};

  // staging: per group, 256 threads x 4 x 16B chunks (2 K + 2 Vt)
  const int tl = tid & 255;
  const int c0 = tl, c1 = tl + 256;
  const int kbase = grp * 1024;  // this group's first key
  const unsigned short* gK0 = K + hb + (size_t)(kbase + (c0 >> 3)) * 64 + (c0 & 7) * 8;
  const unsigned short* gK1 = K + hb + (size_t)(kbase + (c1 >> 3)) * 64 + (c1 & 7) * 8;
  const unsigned short* gV0 = Vt + hb + (size_t)(c0 >> 3) * 2048 + kbase + (c0 & 7) * 8;
  const unsigned short* gV1 = Vt + hb + (size_t)(c1 >> 3) * 2048 + kbase + (c1 & 7) * 8;
  const int sK0 = (c0 >> 3) * 72 + (c0 & 7) * 8;
  const int sK1 = (c1 >> 3) * 72 + (c1 & 7) * 8;
  const int sV0 = 4608 + sK0;
  const int sV1 = 4608 + sK1;

  u32x4 pk0 = *(const u32x4*)gK0, pk1 = *(const u32x4*)gK1;
  u32x4 pv0 = *(const u32x4*)gV0, pv1 = *(const u32x4*)gV1;
  {
    unsigned short* s0b = sm[grp][0];
    *(u32x4*)(s0b + sK0) = pk0; *(u32x4*)(s0b + sK1) = pk1;
    *(u32x4*)(s0b + sV0) = pv0; *(u32x4*)(s0b + sV1) = pv1;
  }
  __syncthreads();

  for (int kb = 0; kb < 1024; kb += 64) {
    const int cur = (kb >> 6) & 1;
    const bool more = (kb + 64) < 1024;
    if (more) {
      pk0 = *(const u32x4*)(gK0 + (size_t)(kb + 64) * 64);
      pk1 = *(const u32x4*)(gK1 + (size_t)(kb + 64) * 64);
      pv0 = *(const u32x4*)(gV0 + kb + 64);
      pv1 = *(const u32x4*)(gV1 + kb + 64);
    }
    const unsigned short* Ks = sm[grp][cur];
    const unsigned short* Vts = sm[grp][cur] + 4608;

    // K A-frags: A[m=key][k=hd]: lane l16 = key (per subtile ks), contiguous hd
    bf16x8 kf[4][2];
#pragma unroll
    for (int ks = 0; ks < 4; ++ks)
#pragma unroll
      for (int st = 0; st < 2; ++st)
        kf[ks][st] = *(const bf16x8*)(Ks + (ks * 16 + l16) * 72 + st * 32 + quad * 8);

    // V B-frags under sigma: two b64 chunks (keys st*32+quad*4+{0..3}, +16)
    bf16x8 vf[4][2];
#pragma unroll
    for (int os = 0; os < 4; ++os)
#pragma unroll
      for (int st = 0; st < 2; ++st) {
        const unsigned short* rb = Vts + (os * 16 + l16) * 72 + st * 32 + quad * 4;
        bf16x4 a = *(const bf16x4*)rb;
        bf16x4 b2 = *(const bf16x4*)(rb + 16);
        vf[os][st] = __builtin_shufflevector(a, b2, 0, 1, 2, 3, 4, 5, 6, 7);
      }

#pragma unroll
    for (int qt = 0; qt < 4; ++qt) {
      // S^T tiles: rows = keys (quad*4+r), cols = qrows (l16)
      f32x4 sc[4];
#pragma unroll
      for (int ks = 0; ks < 4; ++ks) {
        f32x4 a = {0.f, 0.f, 0.f, 0.f};
        a = MFMA16(kf[ks][0], qf[qt][0], a);
        a = MFMA16(kf[ks][1], qf[qt][1], a);
        sc[ks] = a;
      }
      // exp2 -> P A-frags in-register; per-lane l partials (all for qrow l16)
      bf16x8 pf[2];
      float ls = 0.f;
#pragma unroll
      for (int ks = 0; ks < 4; ++ks)
#pragma unroll
        for (int r = 0; r < 4; ++r) {
          float p = __builtin_amdgcn_exp2f(sc[ks][r]);
          ls += p;
          pf[ks >> 1][(ks & 1) * 4 + r] = (__bf16)p;
        }
      lacc[qt] += ls;
#pragma unroll
      for (int st = 0; st < 2; ++st)
#pragma unroll
        for (int os = 0; os < 4; ++os)
          o[qt][os] = MFMA16(pf[st], vf[os][st], o[qt][os]);
    }

    if (more) {
      unsigned short* sn = sm[grp][cur ^ 1];
      *(u32x4*)(sn + sK0) = pk0; *(u32x4*)(sn + sK1) = pk1;
      *(u32x4*)(sn + sV0) = pv0; *(u32x4*)(sn + sV1) = pv1;
    }
    __syncthreads();
  }

  // intra-group: reduce l across quads -> lane holds group row-sum for qrow qt*16+l16
  float lrow[4];
#pragma unroll
  for (int qt = 0; qt < 4; ++qt) {
    float l = lacc[qt];
    l += __shfl_xor(l, 16, 64);
    l += __shfl_xor(l, 32, 64);
    lrow[qt] = l;
  }

  // cross-group combine through LDS (K/V tiles dead after loop-final barrier)
  float* oL = (float*)&sm[0][0][0];       // [w4][qrow 0..63][col 0..63] = 64 KB
  float* lL = oL + 16384;                 // [w4][qt][l16] = 1 KB
  if (grp == 1) {
#pragma unroll
    for (int qt = 0; qt < 4; ++qt) {
#pragma unroll
      for (int os = 0; os < 4; ++os)
#pragma unroll
        for (int r = 0; r < 4; ++r)
          oL[w4 * 4096 + (qt * 16 + quad * 4 + r) * 64 + os * 16 + l16] = o[qt][os][r];
      if (quad == 0) lL[w4 * 64 + qt * 16 + l16] = lrow[qt];
    }
  }
  __syncthreads();

  if (grp == 0) {
    const int b = bh >> 4, h = bh & 15;
#pragma unroll
    for (int qt = 0; qt < 4; ++qt) {
      float l = lrow[qt] + lL[w4 * 64 + qt * 16 + l16];
#pragma unroll
      for (int r = 0; r < 4; ++r) {
        float lr = __shfl(l, quad * 4 + r, 16);
        float inv = 1.0f / lr;
        int s = q0 + qt * 16 + quad * 4 + r;
#pragma unroll
        for (int os = 0; os < 4; ++os) {
          float ov = o[qt][os][r] + oL[w4 * 4096 + (qt * 16 + quad * 4 + r) * 64 + os * 16 + l16];
          ctx[((size_t)(b * 2048 + s)) * 1024 + h * 64 + os * 16 + l16] = f2bf(ov * inv);
        }
      }
    }
  }
}

// ---------------------------------------------------------------- launch
extern "C" void kernel_launch(void* const* d_in, const int* in_sizes, int n_in,
                              void* d_out, int out_size, void* d_ws, size_t ws_size,
                              hipStream_t stream) {
  const float* x  = (const float*)d_in[0];
  const float* Wq = (const float*)d_in[1];
  const float* bq = (const float*)d_in[2];
  const float* Wk = (const float*)d_in[3];
  const float* bk = (const float*)d_in[4];
  const float* Wv = (const float*)d_in[5];
  const float* bv = (const float*)d_in[6];
  const float* Wo = (const float*)d_in[7];
  const float* bo = (const float*)d_in[8];

  unsigned short* ws = (unsigned short*)d_ws;
  unsigned short* xb    = ws;                    // 8388608 (aliased by VtG later)
  unsigned short* Wtall = ws + 8388608;          // 4*1048576 (Wq^T|Wk^T|Wv^T|Wo^T)
  unsigned short* Wot   = Wtall + 3145728;
  unsigned short* Qb    = Wtall + 4194304;       // 8388608  [bh][s][hd], pre-scaled
  unsigned short* Kb    = Qb + 8388608;          // 8388608
  unsigned short* Vb    = Kb + 8388608;          // 8388608
  unsigned short* VtG   = xb;                    // alias: xb dead after QKV GEMM
  unsigned short* Cb    = Vb;                    // alias: Vb dead after transpose_v

  cast_x_kernel<<<8192, 256, 0, stream>>>(x, xb, 2097152);
  transpose_cast4<<<dim3(32, 32, 4), dim3(32, 8), 0, stream>>>(Wq, Wk, Wv, Wo, Wtall);

  gemm128<1><<<dim3(24, 64), 256, 0, stream>>>(xb, Wtall, bq, bk, bv, Qb);
  transpose_v<<<dim3(32, 64), 256, 0, stream>>>(Vb, VtG);
  attn_kernel<<<dim3(8, 64), 512, 0, stream>>>(Qb, Kb, VtG, Cb);
  gemm128<0><<<dim3(8, 64), 256, 0, stream>>>(Cb, Wot, bo, nullptr, nullptr, d_out);
}

// Round 6
// 278.252 us; speedup vs baseline: 1.5299x; 1.0008x over previous
//
#include <hip/hip_runtime.h>
#include <stdint.h>

// B=4, S=2048, D=1024, H=16, Hd=64, M=8192.
// Pipeline: cast x -> bf16; merged W^T casts; merged QKV GEMM (Q pre-scaled
// by log2e/8, V written directly transposed as [bh][hd][s]); flash attn with
// 32x32x16 MFMA computing S^T = K@Q^T so exp2(scores) re-slice directly into
// PV A-frags (sigma key-permutation; no P LDS round-trip); O-proj GEMM.
// R6: attn 32x32 MFMA (half the MFMA/K-frag instrs), stride-68 all-b64 LDS
// (2-way = free), transpose_v fused into QKV epilogue, XCD-swizzled grid.
// NOTE: __launch_bounds__ 2nd arg acts as min BLOCKS/CU (R4: (512,4) caused
// a 64-VGPR cap and 1 GB of scratch spill).

typedef float f32x2 __attribute__((ext_vector_type(2)));
typedef float f32x4 __attribute__((ext_vector_type(4)));
typedef float f32x16 __attribute__((ext_vector_type(16)));
typedef __bf16 bf16x4 __attribute__((ext_vector_type(4)));
typedef __bf16 bf16x8 __attribute__((ext_vector_type(8)));
typedef uint32_t u32x2 __attribute__((ext_vector_type(2)));
typedef uint32_t u32x4 __attribute__((ext_vector_type(4)));

#define MFMA16(a, b, c) __builtin_amdgcn_mfma_f32_16x16x32_bf16((a), (b), (c), 0, 0, 0)
#define MFMA32(a, b, c) __builtin_amdgcn_mfma_f32_32x32x16_bf16((a), (b), (c), 0, 0, 0)

// Q pre-scale: log2(e)/8 so attn does p = exp2(Q'.K) = e^{QK/8} (unnormalized)
#define QSCALE 0.1803368801111204f

__device__ __forceinline__ unsigned short f2bf(float f) {
  union { float f; uint32_t u; } c; c.f = f;
  uint32_t u = c.u;
  return (unsigned short)((u + 0x7fffu + ((u >> 16) & 1u)) >> 16);  // RNE
}

// ---------------------------------------------------------------- casts
__global__ __launch_bounds__(256) void cast_x_kernel(const float* __restrict__ in,
                                                     unsigned short* __restrict__ out,
                                                     int n4) {
  int i = blockIdx.x * 256 + threadIdx.x;
  if (i >= n4) return;
  float4 v = ((const float4*)in)[i];
  ushort4 o;
  o.x = f2bf(v.x); o.y = f2bf(v.y); o.z = f2bf(v.z); o.w = f2bf(v.w);
  ((ushort4*)out)[i] = o;
}

// 4 weights [k][n] fp32 -> Wt [n][k] bf16, z selects matrix; dst contiguous.
__global__ __launch_bounds__(256) void transpose_cast4(const float* __restrict__ W0,
                                                       const float* __restrict__ W1,
                                                       const float* __restrict__ W2,
                                                       const float* __restrict__ W3,
                                                       unsigned short* __restrict__ Wt) {
  __shared__ float tile[32][33];
  const int z = blockIdx.z;
  const float* W = (z == 0) ? W0 : (z == 1) ? W1 : (z == 2) ? W2 : W3;
  unsigned short* dst = Wt + (size_t)z * 1048576;
  int k0 = blockIdx.x * 32, n0 = blockIdx.y * 32;
  int tx = threadIdx.x, ty = threadIdx.y;
#pragma unroll
  for (int i = 0; i < 32; i += 8)
    tile[ty + i][tx] = W[(size_t)(k0 + ty + i) * 1024 + n0 + tx];
  __syncthreads();
#pragma unroll
  for (int i = 0; i < 32; i += 8)
    dst[(size_t)(n0 + ty + i) * 1024 + k0 + tx] = f2bf(tile[tx][ty + i]);
}

// ---------------------------------------------------------------- GEMM
// MODE 0: O-proj. out fp32 [8192][1024], bias b0.
// MODE 1: merged QKV. Bt = [3072][1024]. Q (mb=0, scaled) and K (mb=1) scatter
//         bf16 to out=[bh][s][hd]; V (mb=2) writes vout=[bh][hd][s] (8B packed).
template <int MODE>
__global__ __launch_bounds__(256) void gemm128(const unsigned short* __restrict__ A,
                                               const unsigned short* __restrict__ Bt,
                                               const float* __restrict__ b0,
                                               const float* __restrict__ b1,
                                               const float* __restrict__ b2,
                                               void* __restrict__ out,
                                               unsigned short* __restrict__ vout) {
  constexpr int Kd = 1024;
  __shared__ unsigned short sm[128 * 32 + 32 * 128];
  unsigned short* As = sm;
  unsigned short* Bs = sm + 128 * 32;
  auto lds3 = (__attribute__((address_space(3))) char*)sm;

  const int tid = threadIdx.x;
  const int wave = tid >> 6, lane = tid & 63, quad = lane >> 4, l16 = lane & 15;
  const int wm = wave >> 1, wn = wave & 1;
  const int bm = blockIdx.y * 128, bn = blockIdx.x * 128;

  f32x4 acc[4][4] = {};

  for (int k0 = 0; k0 < Kd; k0 += 32) {
#pragma unroll
    for (int j = 0; j < 2; ++j) {
      int i = (wave * 2 + j) * 64 + lane;  // 16B-chunk index 0..511
      const unsigned short* ga = A + (size_t)(bm + (i >> 2)) * Kd + k0 + (i & 3) * 8;
      __builtin_amdgcn_global_load_lds(
          (const __attribute__((address_space(1))) void*)ga,
          (__attribute__((address_space(3))) void*)(lds3 + (size_t)(wave * 2 + j) * 1024),
          16, 0, 0);
      const unsigned short* gb = Bt + (size_t)(bn + (i >> 2)) * Kd + k0 + (i & 3) * 8;
      __builtin_amdgcn_global_load_lds(
          (const __attribute__((address_space(1))) void*)gb,
          (__attribute__((address_space(3))) void*)(lds3 + 8192 + (size_t)(wave * 2 + j) * 1024),
          16, 0, 0);
    }
    __syncthreads();

    bf16x8 af[4], bfv[4];
#pragma unroll
    for (int i = 0; i < 4; ++i)
      af[i] = *(const bf16x8*)(As + (wm * 64 + i * 16 + l16) * 32 + quad * 8);
#pragma unroll
    for (int n = 0; n < 4; ++n)
      bfv[n] = *(const bf16x8*)(Bs + (wn * 64 + n * 16 + l16) * 32 + quad * 8);
#pragma unroll
    for (int i = 0; i < 4; ++i)
#pragma unroll
      for (int n = 0; n < 4; ++n)
        acc[i][n] = MFMA16(af[i], bfv[n], acc[i][n]);
    __syncthreads();
  }

  // epilogue: C/D layout col=lane&15, row=quad*4+reg
  const int mb = bn >> 10;  // matrix id for MODE 1 (block never straddles: 1024%128==0)
  const float* bias = (MODE == 0) ? b0 : (mb == 0 ? b0 : (mb == 1 ? b1 : b2));
  const float scale = (MODE == 1 && mb == 0) ? QSCALE : 1.0f;
  unsigned short* oq = (MODE == 1) ? ((unsigned short*)out + (size_t)mb * 8388608u) : nullptr;

#pragma unroll
  for (int i = 0; i < 4; ++i) {
    const int row0 = bm + wm * 64 + i * 16 + quad * 4;
#pragma unroll
    for (int n = 0; n < 4; ++n) {
      const int col = bn + wn * 64 + n * 16 + l16;
      const int cl = col & 1023;
      const float bv = bias[cl];
      float v[4];
#pragma unroll
      for (int r = 0; r < 4; ++r) v[r] = (acc[i][n][r] + bv) * scale;
      if (MODE == 0) {
#pragma unroll
        for (int r = 0; r < 4; ++r)
          ((float*)out)[(size_t)(row0 + r) * 1024 + col] = v[r];
      } else {
        const int b = row0 >> 11, s0 = row0 & 2047;
        const int hh = cl >> 6, hd = cl & 63;
        if (mb < 2) {
#pragma unroll
          for (int r = 0; r < 4; ++r)
            oq[((size_t)(b * 16 + hh) * 2048 + (s0 + r)) * 64 + hd] = f2bf(v[r]);
        } else {
          // V transposed: [bh][hd][s], 4 consecutive s -> one 8B store
          u32x2 w;
          w[0] = (uint32_t)f2bf(v[0]) | ((uint32_t)f2bf(v[1]) << 16);
          w[1] = (uint32_t)f2bf(v[2]) | ((uint32_t)f2bf(v[3]) << 16);
          *(u32x2*)(vout + (size_t)(b * 16 + hh) * 131072 + (size_t)hd * 2048 + s0) = w;
        }
      }
    }
  }
}

// ---------------------------------------------------------------- flash attention
// Q pre-scaled. Block = (b,h) x 256 q-rows, 256 threads (4 waves x 64 q-rows).
// 32x32x16 MFMA. S^T = K(A) @ Q^T(B): C layout col=l32=qrow,
// row=(reg&3)+8*(reg>>2)+4*hf = key. Under sigma(hf*8+j) = 4*hf + (j&3) + 8*(j>>2),
// the PV A-frag for key-half m2 is exactly pf[m2][j] = exp2(sc[8*m2+j]) — a pure
// register re-slice. V B-frags = two b64 from Vt tile at key offset m2*16+4*hf (+8).
// LDS stride 68 ush (34 dw == 2 mod 32): all b64 accesses 2-way (free).
__global__ __launch_bounds__(256, 2) void attn_kernel(const unsigned short* __restrict__ Q,
                                                      const unsigned short* __restrict__ K,
                                                      const unsigned short* __restrict__ Vt,
                                                      unsigned short* __restrict__ ctx) {
  const int blk = blockIdx.x;
  // XCD swizzle: blocks with equal blk%8 share 8 heads (round-robin heuristic)
  const int bh = (blk & 7) * 8 + ((blk >> 3) & 7);
  const int qt8 = blk >> 6;
  const int tid = threadIdx.x;
  const int wave = tid >> 6, lane = tid & 63, l32 = lane & 31, hf = lane >> 5;

  __shared__ unsigned short sm[2][2 * 4352];  // [buf][K 64x68 | Vt 64x68]

  const size_t hb = (size_t)bh * 131072;
  const int q0 = qt8 * 256 + wave * 64;

  // Q B-frags: qf[qt][kc]: B[k=hf*8+j][n=l32], hd = kc*16 + hf*8 + j
  bf16x8 qf[2][4];
#pragma unroll
  for (int qt = 0; qt < 2; ++qt)
#pragma unroll
    for (int kc = 0; kc < 4; ++kc)
      qf[qt][kc] = *(const bf16x8*)(Q + hb + (size_t)(q0 + qt * 32 + l32) * 64 + kc * 16 + hf * 8);

  f32x16 o[2][2] = {};   // [qt][hdt]
  f32x2 lacc[2] = {};
  const f32x16 z16 = {};

  // staging: 4 x 16B chunks/thread (2 K + 2 Vt), written as b64 pairs
  const int c0 = tid, c1 = tid + 256;
  const unsigned short* gK0 = K + hb + (size_t)(c0 >> 3) * 64 + (c0 & 7) * 8;
  const unsigned short* gK1 = K + hb + (size_t)(c1 >> 3) * 64 + (c1 & 7) * 8;
  const unsigned short* gV0 = Vt + hb + (size_t)(c0 >> 3) * 2048 + (c0 & 7) * 8;
  const unsigned short* gV1 = Vt + hb + (size_t)(c1 >> 3) * 2048 + (c1 & 7) * 8;
  const int sK0 = (c0 >> 3) * 68 + (c0 & 7) * 8;
  const int sK1 = (c1 >> 3) * 68 + (c1 & 7) * 8;
  const int sV0 = 4352 + sK0;
  const int sV1 = 4352 + sK1;

  u32x4 pk0 = *(const u32x4*)gK0, pk1 = *(const u32x4*)gK1;
  u32x4 pv0 = *(const u32x4*)gV0, pv1 = *(const u32x4*)gV1;
  {
    unsigned short* sb = sm[0];
    *(u32x2*)(sb + sK0) = (u32x2){pk0[0], pk0[1]}; *(u32x2*)(sb + sK0 + 4) = (u32x2){pk0[2], pk0[3]};
    *(u32x2*)(sb + sK1) = (u32x2){pk1[0], pk1[1]}; *(u32x2*)(sb + sK1 + 4) = (u32x2){pk1[2], pk1[3]};
    *(u32x2*)(sb + sV0) = (u32x2){pv0[0], pv0[1]}; *(u32x2*)(sb + sV0 + 4) = (u32x2){pv0[2], pv0[3]};
    *(u32x2*)(sb + sV1) = (u32x2){pv1[0], pv1[1]}; *(u32x2*)(sb + sV1 + 4) = (u32x2){pv1[2], pv1[3]};
  }
  __syncthreads();

  for (int kb = 0; kb < 2048; kb += 64) {
    const int cur = (kb >> 6) & 1;
    const bool more = (kb + 64) < 2048;
    if (more) {
      pk0 = *(const u32x4*)(gK0 + (size_t)(kb + 64) * 64);
      pk1 = *(const u32x4*)(gK1 + (size_t)(kb + 64) * 64);
      pv0 = *(const u32x4*)(gV0 + kb + 64);
      pv1 = *(const u32x4*)(gV1 + kb + 64);
    }
    const unsigned short* Ks = sm[cur];
    const unsigned short* Vs = sm[cur] + 4352;

#pragma unroll
    for (int ks = 0; ks < 2; ++ks) {
      // K A-frags: A[m=l32=key][k=hf*8+j], hd = kc*16 + hf*8 + j
      bf16x8 kf[4];
#pragma unroll
      for (int kc = 0; kc < 4; ++kc) {
        const unsigned short* rb = Ks + (ks * 32 + l32) * 68 + kc * 16 + hf * 8;
        bf16x4 a = *(const bf16x4*)rb;
        bf16x4 b2 = *(const bf16x4*)(rb + 4);
        kf[kc] = __builtin_shufflevector(a, b2, 0, 1, 2, 3, 4, 5, 6, 7);
      }
      // V B-frags under sigma: vf[m2][hdt], two b64 at key m2*16+4*hf (+8)
      bf16x8 vf[2][2];
#pragma unroll
      for (int m2 = 0; m2 < 2; ++m2)
#pragma unroll
        for (int hdt = 0; hdt < 2; ++hdt) {
          const unsigned short* rb = Vs + (hdt * 32 + l32) * 68 + ks * 32 + m2 * 16 + hf * 4;
          bf16x4 a = *(const bf16x4*)rb;
          bf16x4 b2 = *(const bf16x4*)(rb + 8);
          vf[m2][hdt] = __builtin_shufflevector(a, b2, 0, 1, 2, 3, 4, 5, 6, 7);
        }

#pragma unroll
      for (int qt = 0; qt < 2; ++qt) {
        f32x16 sc = MFMA32(kf[0], qf[qt][0], z16);
        sc = MFMA32(kf[1], qf[qt][1], sc);
        sc = MFMA32(kf[2], qf[qt][2], sc);
        sc = MFMA32(kf[3], qf[qt][3], sc);

        bf16x8 pf0, pf1;
#pragma unroll
        for (int j = 0; j < 8; j += 2) {
          float pa = __builtin_amdgcn_exp2f(sc[j]);
          float pb = __builtin_amdgcn_exp2f(sc[j + 1]);
          float pc = __builtin_amdgcn_exp2f(sc[8 + j]);
          float pd = __builtin_amdgcn_exp2f(sc[9 + j]);
          lacc[qt] += (f32x2){pa, pb};
          lacc[qt] += (f32x2){pc, pd};
          pf0[j] = (__bf16)pa; pf0[j + 1] = (__bf16)pb;
          pf1[j] = (__bf16)pc; pf1[j + 1] = (__bf16)pd;
        }
        o[qt][0] = MFMA32(pf0, vf[0][0], o[qt][0]);
        o[qt][1] = MFMA32(pf0, vf[0][1], o[qt][1]);
        o[qt][0] = MFMA32(pf1, vf[1][0], o[qt][0]);
        o[qt][1] = MFMA32(pf1, vf[1][1], o[qt][1]);
      }
    }

    if (more) {
      unsigned short* sn = sm[cur ^ 1];
      *(u32x2*)(sn + sK0) = (u32x2){pk0[0], pk0[1]}; *(u32x2*)(sn + sK0 + 4) = (u32x2){pk0[2], pk0[3]};
      *(u32x2*)(sn + sK1) = (u32x2){pk1[0], pk1[1]}; *(u32x2*)(sn + sK1 + 4) = (u32x2){pk1[2], pk1[3]};
      *(u32x2*)(sn + sV0) = (u32x2){pv0[0], pv0[1]}; *(u32x2*)(sn + sV0 + 4) = (u32x2){pv0[2], pv0[3]};
      *(u32x2*)(sn + sV1) = (u32x2){pv1[0], pv1[1]}; *(u32x2*)(sn + sV1 + 4) = (u32x2){pv1[2], pv1[3]};
    }
    __syncthreads();
  }

  // finalize: l per qrow lives at lane l32 (both halves after xor-32);
  // redistribute to C-layout rows via bpermute, normalize, store.
  const int b = bh >> 4, hh = bh & 15;
#pragma unroll
  for (int qt = 0; qt < 2; ++qt) {
    float l = lacc[qt][0] + lacc[qt][1];
    l += __shfl_xor(l, 32, 64);
#pragma unroll
    for (int reg = 0; reg < 16; ++reg) {
      const int row = (reg & 3) + 8 * (reg >> 2) + 4 * hf;
      const float inv = 1.0f / __shfl(l, row, 32);
      const int s = q0 + qt * 32 + row;
      const size_t base = ((size_t)(b * 2048 + s)) * 1024 + hh * 64;
      ctx[base + l32] = f2bf(o[qt][0][reg] * inv);
      ctx[base + 32 + l32] = f2bf(o[qt][1][reg] * inv);
    }
  }
}

// ---------------------------------------------------------------- launch
extern "C" void kernel_launch(void* const* d_in, const int* in_sizes, int n_in,
                              void* d_out, int out_size, void* d_ws, size_t ws_size,
                              hipStream_t stream) {
  const float* x  = (const float*)d_in[0];
  const float* Wq = (const float*)d_in[1];
  const float* bq = (const float*)d_in[2];
  const float* Wk = (const float*)d_in[3];
  const float* bk = (const float*)d_in[4];
  const float* Wv = (const float*)d_in[5];
  const float* bv = (const float*)d_in[6];
  const float* Wo = (const float*)d_in[7];
  const float* bo = (const float*)d_in[8];

  unsigned short* ws = (unsigned short*)d_ws;
  unsigned short* xb    = ws;                    // 8388608
  unsigned short* Wtall = ws + 8388608;          // 4*1048576 (Wq^T|Wk^T|Wv^T|Wo^T)
  unsigned short* Wot   = Wtall + 3145728;
  unsigned short* Qb    = Wtall + 4194304;       // 8388608  [bh][s][hd], pre-scaled
  unsigned short* Kb    = Qb + 8388608;          // 8388608  [bh][s][hd]
  unsigned short* VtG   = Kb + 8388608;          // 8388608  [bh][hd][s]
  unsigned short* Cb    = VtG + 8388608;         // 8388608  [b][s][1024]
  // total 92,274,688 bytes

  cast_x_kernel<<<8192, 256, 0, stream>>>(x, xb, 2097152);
  transpose_cast4<<<dim3(32, 32, 4), dim3(32, 8), 0, stream>>>(Wq, Wk, Wv, Wo, Wtall);

  gemm128<1><<<dim3(24, 64), 256, 0, stream>>>(xb, Wtall, bq, bk, bv, Qb, VtG);
  attn_kernel<<<512, 256, 0, stream>>>(Qb, Kb, VtG, Cb);
  gemm128<0><<<dim3(8, 64), 256, 0, stream>>>(Cb, Wot, bo, nullptr, nullptr, d_out, nullptr);
}